// Round 17
// baseline (199.422 us; speedup 1.0000x reference)
//
#include <hip/hip_runtime.h>

// GNNCriticEncoder fused kernel v19 (MI355X / gfx950)
// ROOT CAUSE (converged via v14-pass vs v18-fail bisect): schedule-dependent latent
// hazard, not semantics. The ONE inline-asm site consuming RAW MFMA accumulator
// values is the hT-write pk2(a[0],a[1]): MFMA->VALU reads need hazard wait states;
// the hazard recognizer treats INLINEASM as opaque and omits them (same family as
// v4's TRANS bug). Green versions were schedule luck (alpha's plain-C FMAs landed
// between MFMA and pk2); restructures (v13/v16/v17/v18) broke the luck.
// v19 = v18 (runtime-nj persistent blocks, v14-proven semantics) with the hT pack
// done via plain-C f2bf (compiler-known reads -> waits inserted; identical RNE).
// All other pk2 sites are VALU-fed (safe, unchanged).
// ws = exactly 81920 B (do not exceed).

#define NTOK 32
#define EMB  128
#define OBSL 1056
#define XSTR 136   // x row stride in shorts (272 B, 16B-aligned rows)
#define HSTR 40    // hT row stride in shorts (80 B: 16B-aligned)

typedef __attribute__((ext_vector_type(8))) short  short8;   // 8 x bf16 MFMA A/B frag (4 VGPR)
typedef __attribute__((ext_vector_type(4))) float  floatx4;  // MFMA C/D frag (4 VGPR)
typedef __attribute__((ext_vector_type(2))) unsigned uint2v;

__device__ __forceinline__ short f2bf(float f) {             // scalar RNE, plain C (hazard-safe)
  union { float f; unsigned u; } v; v.f = f;
  unsigned r = (v.u + 0x7fffu + ((v.u >> 16) & 1u)) >> 16;
  return (short)(unsigned short)r;
}
// HW packed fp32->bf16 (RNE): inline asm -- ONLY safe on VALU-computed inputs
// (compiler-known producers get hazard waits). NEVER feed raw MFMA results.
__device__ __forceinline__ unsigned pk2(float a, float b) {
  unsigned r; asm("v_cvt_pk_bf16_f32 %0, %1, %2" : "=v"(r) : "v"(a), "v"(b)); return r;
}
__device__ __forceinline__ float exp2_hw(float x) {
#if __has_builtin(__builtin_amdgcn_exp2f)
  return __builtin_amdgcn_exp2f(x);
#else
  return exp2f(x);
#endif
}
__device__ __forceinline__ float rcp_hw(float x) {
#if __has_builtin(__builtin_amdgcn_rcpf)
  return __builtin_amdgcn_rcpf(x);
#else
  return 1.0f / x;
#endif
}
__device__ __forceinline__ float elu1(float v) { return v > 0.f ? v : __expf(v) - 1.f; }
__device__ __forceinline__ floatx4 mfma16(short8 a, short8 b, floatx4 c) {
  return __builtin_amdgcn_mfma_f32_16x16x32_bf16(a, b, c, 0, 0, 0);
}

// ws layout (bf16): [0,8192) embT[e][k] (k<40 Wv, else Wp) | [8192,24576) wT0[e][k] | [24576,40960) wT1[e][k]
// Total: 40960 shorts = exactly 81920 B. DO NOT EXCEED (ws_size appears to be 80 KiB).
__global__ void prep_weights(const float* __restrict__ Wv, const float* __restrict__ Wp,
                             const float* __restrict__ w0, const float* __restrict__ w1,
                             short* __restrict__ ws) {
  int idx = blockIdx.x * 256 + threadIdx.x;          // 160 blocks x 256 = 40960
  if (idx < 8192) {
    int e = idx >> 6, k = idx & 63;
    float v = (k < 40) ? Wv[(size_t)k * EMB + e] : Wp[(size_t)(k - 40) * EMB + e];
    ws[idx] = f2bf(v);
  } else if (idx < 24576) {
    int t = idx - 8192; int e = t >> 7, k = t & 127;
    ws[idx] = f2bf(w0[(size_t)k * EMB + e]);
  } else {
    int t = idx - 24576; int e = t >> 7, k = t & 127;
    ws[idx] = f2bf(w1[(size_t)k * EMB + e]);
  }
}

__global__ __launch_bounds__(256, 6) void gnn_fused(
    const float* __restrict__ obs,
    const float* __restrict__ bv, const float* __restrict__ bp,
    const float* __restrict__ as0, const float* __restrict__ ad0,
    const float* __restrict__ as1, const float* __restrict__ ad1,
    const short* __restrict__ wsb,
    float* __restrict__ out, int nj)
{
  __shared__ __align__(16) short s_x[32 * XSTR];       // 8704 B: x[token][e]
  __shared__ __align__(16) short s_h[4 * 32 * HSTR];   // 10240 B: 4 wave-private hT quarters

  const int tid  = threadIdx.x;
  const int lane = tid & 63;
  const int wv   = tid >> 6;      // 0..3 = head; e-rows [32wv,32wv+32); m-tiles {2wv,2wv+1}
  const int col  = lane & 15;
  const int quad = lane >> 4;

  short* hbase = &s_h[wv * 1280];               // own hT quarter: [32 e-loc][HSTR]
  const short8  z8 = {0,0,0,0,0,0,0,0};
  const floatx4 fz = {0.f,0.f,0.f,0.f};

  #pragma clang loop unroll(disable)
  for (int j = 0; j < nj; ++j) {                // runtime bound: no unroll, no cross-item pipelining
    const size_t b = (size_t)blockIdx.x * nj + j;
    const float* orow = obs + b * OBSL;

    __syncthreads();                            // barJ: prev item's s_x reads done before new writes

    // ---------------- alive mask (wave-uniform), pad, scatter (proven pieces) ----------------
    unsigned m32; float invc;
    {
      float araw = (lane < NTOK) ? orow[1024 + lane] : 0.f;
      bool alv = (lane < NTOK) && (araw >= 0.5f);
      unsigned long long m = __ballot(alv);
      int cnt = __popcll(m);
      unsigned mm = (unsigned)m;
      if (cnt == 0) { mm = 0xFFFFFFFFu; cnt = NTOK; }
      m32 = mm; invc = 1.f / (float)cnt;
    }

    {                                           // complement pad: veh rows cols [40,64), ped rows cols [0,40)
      int idx = tid; int r = -1, k = 0;
      if (idx < 48)       { r = (idx * 171) >> 9;  k = 40 + (idx - r * 3) * 8; }       // /3 magic (idx<48)
      else if (idx < 128) { int t2 = idx - 48; int q5 = (t2 * 205) >> 10; r = 16 + q5; k = (t2 - q5 * 5) * 8; } // /5 magic (t2<80)
      if (r >= 0) *(short8*)&s_x[r * XSTR + k] = z8;
    }
    {                                           // scatter: 256 float4, 64 per wave; disjoint from pad
      int i4 = wv * 64 + lane;
      float4 v = *(const float4*)&orow[i4 * 4];
      int r, k;
      if (i4 < 160) { r = (i4 * 205) >> 11;  k = (i4 - r * 10) * 4; }              // /10 magic (i4<160)
      else { int t2 = i4 - 160; int q6 = (t2 * 171) >> 10; r = 16 + q6; k = 40 + (t2 - q6 * 6) * 4; } // /6 magic (t2<96)
      uint2v u; u.x = pk2(v.x, v.y); u.y = pk2(v.z, v.w);   // VALU/VMEM-fed: safe
      *(uint2v*)&s_x[r * XSTR + k] = u;
    }
    __syncthreads();                            // barS: pad+scatter -> Bxin reads

    // ---------------- P1: embed D[e][tok] (LDS-staged, proven path) ----------------
    {
      short8 Bxin[2][2];                        // full K=64 of x_in
      #pragma unroll
      for (int nt = 0; nt < 2; ++nt)
        #pragma unroll
        for (int kt = 0; kt < 2; ++kt)
          Bxin[nt][kt] = *(const short8*)&s_x[(nt * 16 + col) * XSTR + kt * 32 + quad * 8];
      __syncthreads();                          // barX: Bxin reads -> embed writes
      const short* embT = wsb;
      #pragma unroll
      for (int mi = 0; mi < 2; ++mi) {
        const int mtE = wv * 2 + mi;
        short8 A0 = *(const short8*)&embT[(mtE * 16 + col) * 64 + quad * 8];
        short8 A1 = *(const short8*)&embT[(mtE * 16 + col) * 64 + 32 + quad * 8];
        float4 bv4 = *(const float4*)&bv[mtE * 16 + quad * 4];
        float4 bp4 = *(const float4*)&bp[mtE * 16 + quad * 4];
        #pragma unroll
        for (int nt = 0; nt < 2; ++nt) {
          floatx4 acc = fz;
          acc = mfma16(A0, Bxin[nt][0], acc);
          acc = mfma16(A1, Bxin[nt][1], acc);
          float4 bb = nt ? bp4 : bv4;
          // pk2 inputs are VALU add results (acc+bias): safe
          uint2v u; u.x = pk2(acc[0] + bb.x, acc[1] + bb.y); u.y = pk2(acc[2] + bb.z, acc[3] + bb.w);
          *(uint2v*)&s_x[(nt * 16 + col) * XSTR + mtE * 16 + quad * 4] = u;
        }
      }
    }

    // ---------------- GAT layers (GEMM region frozen at v15's exact form) ----------------
    for (int L = 0; L < 2; ++L) {
      const short* wT  = wsb + 8192 + L * 16384;
      const float* gas = L ? as1 : as0;
      const float* gad = L ? ad1 : ad0;

      __syncthreads();                          // barG: x writes (embed / L0 epilogue) -> GEMM reads

      // hT GEMM, acc-major (v15 exact): 2 m-tiles accumulate across K
      floatx4 acc[2][2];
      #pragma unroll
      for (int mi = 0; mi < 2; ++mi) { acc[mi][0] = fz; acc[mi][1] = fz; }
      #pragma unroll
      for (int kt = 0; kt < 4; ++kt) {
        short8 B0 = *(const short8*)&s_x[(col) * XSTR + kt * 32 + quad * 8];
        short8 B1 = *(const short8*)&s_x[(16 + col) * XSTR + kt * 32 + quad * 8];
        #pragma unroll
        for (int mi = 0; mi < 2; ++mi) {
          const int mt = wv * 2 + mi;
          short8 A = *(const short8*)&wT[(mt * 16 + col) * 128 + kt * 32 + quad * 8];
          acc[mi][0] = mfma16(A, B0, acc[mi][0]);
          acc[mi][1] = mfma16(A, B1, acc[mi][1]);
        }
      }

      // alpha partials (own head) — plain-C reads of acc (hazard-handled)
      float psrc[2], pdst[2];
      psrc[0] = 0.f; psrc[1] = 0.f; pdst[0] = 0.f; pdst[1] = 0.f;
      #pragma unroll
      for (int mi = 0; mi < 2; ++mi) {
        const int mt = wv * 2 + mi;
        float4 cs = *(const float4*)&gas[mt * 16 + quad * 4];
        float4 cd = *(const float4*)&gad[mt * 16 + quad * 4];
        #pragma unroll
        for (int nt = 0; nt < 2; ++nt) {
          floatx4 a = acc[mi][nt];
          psrc[nt] += a[0]*cs.x + a[1]*cs.y + a[2]*cs.z + a[3]*cs.w;
          pdst[nt] += a[0]*cd.x + a[1]*cd.y + a[2]*cd.z + a[3]*cd.w;
        }
      }

      // hT writes into own (wave-private) quarter.
      // f2bf (plain C), NOT pk2: inline asm reading raw MFMA accumulators lacks
      // hazard-recognizer wait states -> schedule-dependent corruption (the v13/
      // v16/v17/v18 red series). f2bf is bit-identical RNE.
      #pragma unroll
      for (int mi = 0; mi < 2; ++mi) {
        const int rowloc = mi * 16 + quad * 4;  // e-local row within quarter
        #pragma unroll
        for (int nt = 0; nt < 2; ++nt) {
          floatx4 a = acc[mi][nt];
          unsigned short* hrow = (unsigned short*)&hbase[rowloc * HSTR + nt * 16 + col];
          hrow[0]        = (unsigned short)f2bf(a[0]);
          hrow[HSTR]     = (unsigned short)f2bf(a[1]);
          hrow[2 * HSTR] = (unsigned short)f2bf(a[2]);
          hrow[3 * HSTR] = (unsigned short)f2bf(a[3]);
        }
      }

      // full per-token alpha in every lane (token = nt*16 + col), exp2 domain
      #pragma unroll
      for (int nt = 0; nt < 2; ++nt) {
        float vs = psrc[nt]; vs += __shfl_xor(vs, 16); vs += __shfl_xor(vs, 32);
        psrc[nt] = vs * 1.44269504088896340736f;
        float vd = pdst[nt]; vd += __shfl_xor(vd, 16); vd += __shfl_xor(vd, 32);
        pdst[nt] = vd * 1.44269504088896340736f;
      }

      // softmax (own head), PV B-frag layout: lane owns (i = ii*16+col, key = quad*8+jj)
      short8 pf[2];
      {
        float vsel = (quad >> 1) ? pdst[1] : pdst[0];
        float ad8[8];
        #pragma unroll
        for (int jj = 0; jj < 8; ++jj) {
          float v = __shfl(vsel, ((quad >> 1) << 5) + ((quad & 1) << 3) + jj);
          bool alive = (m32 >> (quad * 8 + jj)) & 1u;        // SGPR mask test
          ad8[jj] = alive ? v : -1e30f;                      // dead keys -> exp2 -> 0
        }
        #pragma unroll
        for (int ii = 0; ii < 2; ++ii) {
          float ai = psrc[ii];
          float ev[8]; float sum = 0.f;
          #pragma unroll
          for (int jj = 0; jj < 8; ++jj) {
            float e = ai + ad8[jj];
            e = fmaxf(e, 0.2f * e);                          // leaky-relu (commutes with log2e scale)
            float p = exp2_hw(e);
            ev[jj] = p; sum += p;
          }
          sum += __shfl_xor(sum, 16);
          sum += __shfl_xor(sum, 32);
          float inv = rcp_hw(sum);
          union { unsigned u4[4]; short8 s; } pu;
          #pragma unroll
          for (int p2 = 0; p2 < 4; ++p2) pu.u4[p2] = pk2(ev[2*p2] * inv, ev[2*p2+1] * inv); // VALU-fed: safe
          pf[ii] = pu.s;
        }
      }

      // PV A-frags from own quarter (same-wave), proven position: BEFORE barE
      short8 Ah[2];
      #pragma unroll
      for (int mt2 = 0; mt2 < 2; ++mt2)
        Ah[mt2] = *(const short8*)&hbase[(mt2 * 16 + col) * HSTR + quad * 8];
      if (L == 0) __syncthreads();              // barE: ALL waves' GEMM x-reads done -> x_next writes

      #pragma unroll
      for (int mt2 = 0; mt2 < 2; ++mt2) {
        floatx4 po[2];
        #pragma unroll
        for (int nt = 0; nt < 2; ++nt) {
          po[nt] = mfma16(Ah[mt2], pf[nt], fz);
        }
        const int ecol = wv * 32 + mt2 * 16 + quad * 4;  // global e
        if (L == 0) {
          #pragma unroll
          for (int nt = 0; nt < 2; ++nt) {
            // pk2 inputs are elu1() VALU results: safe
            uint2v u;
            u.x = pk2(elu1(po[nt][0]), elu1(po[nt][1]));
            u.y = pk2(elu1(po[nt][2]), elu1(po[nt][3]));
            *(uint2v*)&s_x[(nt * 16 + col) * XSTR + ecol] = u;
          }
        } else {
          float aI0 = ((m32 >> col) & 1u) ? 1.f : 0.f;         // alive of token col
          float aI1 = ((m32 >> (16 + col)) & 1u) ? 1.f : 0.f;  // alive of token 16+col
          #pragma unroll
          for (int r = 0; r < 4; ++r) {
            float s = elu1(po[0][r]) * aI0 + elu1(po[1][r]) * aI1;
            s += __shfl_xor(s, 1); s += __shfl_xor(s, 2);
            s += __shfl_xor(s, 4); s += __shfl_xor(s, 8);
            if (col == 0) out[b * EMB + ecol + r] = s * invc;  // direct store (proven path)
          }
        }
      }
    }
  }
}

extern "C" void kernel_launch(void* const* d_in, const int* in_sizes, int n_in,
                              void* d_out, int out_size, void* d_ws, size_t ws_size,
                              hipStream_t stream) {
  const float* obs = (const float*)d_in[0];
  const float* Wv  = (const float*)d_in[1];
  const float* bv  = (const float*)d_in[2];
  const float* Wp  = (const float*)d_in[3];
  const float* bp  = (const float*)d_in[4];
  const float* w0  = (const float*)d_in[5];
  const float* as0 = (const float*)d_in[6];
  const float* ad0 = (const float*)d_in[7];
  const float* w1  = (const float*)d_in[8];
  const float* as1 = (const float*)d_in[9];
  const float* ad1 = (const float*)d_in[10];
  float* out = (float*)d_out;
  short* wsb = (short*)d_ws;                      // uses exactly 80 KiB

  int Bn = in_sizes[0] / OBSL;                    // 4096
  prep_weights<<<160, 256, 0, stream>>>(Wv, Wp, w0, w1, wsb);
  gnn_fused<<<Bn / 2, 256, 0, stream>>>(obs, bv, bp, as0, ad0, as1, ad1, wsb, out, 2);
}

// Round 18
// 168.640 us; speedup vs baseline: 1.1825x; 1.1825x over previous
//
#include <hip/hip_runtime.h>

// GNNCriticEncoder fused kernel v20 (MI355X / gfx950)
// v19 CONFIRMED the session-long correctness root cause: inline-asm pk2 reading raw
// MFMA accumulators lacks hazard-recognizer wait states (INLINEASM opaque) ->
// schedule-dependent corruption; f2bf (plain C) fixed it (v18 red -> v19 green).
// v19 also showed sequential-multi-item spills regardless of trip-count form (dead
// end), and occupancy == f(total registers incl AGPRs) in every non-spilled version.
// v20 = v15's proven single-item/block shape (grid 4096) + f2bf hT pack + the
// nt-split GEMM register diet (v17's form, which failed ONLY due to the hazard):
//  - acc[2] (8 AGPRs) live per nt pass instead of acc[2][2] (16); A-frags re-read
//    per nt (VMEM idle, wT L2-resident); per-nt kt/mi order unchanged -> bit-identical.
//  - total regs ~72 -> 6-7 waves/SIMD (v15: ~88 -> 5).
// ws = exactly 81920 B (do not exceed).

#define NTOK 32
#define EMB  128
#define OBSL 1056
#define XSTR 136   // x row stride in shorts (272 B, 16B-aligned rows)
#define HSTR 40    // hT row stride in shorts (80 B: 16B-aligned)

typedef __attribute__((ext_vector_type(8))) short  short8;   // 8 x bf16 MFMA A/B frag (4 VGPR)
typedef __attribute__((ext_vector_type(4))) float  floatx4;  // MFMA C/D frag (4 VGPR)
typedef __attribute__((ext_vector_type(2))) unsigned uint2v;

__device__ __forceinline__ short f2bf(float f) {             // scalar RNE, plain C (hazard-safe)
  union { float f; unsigned u; } v; v.f = f;
  unsigned r = (v.u + 0x7fffu + ((v.u >> 16) & 1u)) >> 16;
  return (short)(unsigned short)r;
}
// HW packed fp32->bf16 (RNE): inline asm -- ONLY safe on VALU-computed inputs
// (compiler-known producers get hazard waits). NEVER feed raw MFMA results.
__device__ __forceinline__ unsigned pk2(float a, float b) {
  unsigned r; asm("v_cvt_pk_bf16_f32 %0, %1, %2" : "=v"(r) : "v"(a), "v"(b)); return r;
}
__device__ __forceinline__ float exp2_hw(float x) {
#if __has_builtin(__builtin_amdgcn_exp2f)
  return __builtin_amdgcn_exp2f(x);
#else
  return exp2f(x);
#endif
}
__device__ __forceinline__ float rcp_hw(float x) {
#if __has_builtin(__builtin_amdgcn_rcpf)
  return __builtin_amdgcn_rcpf(x);
#else
  return 1.0f / x;
#endif
}
__device__ __forceinline__ float elu1(float v) { return v > 0.f ? v : __expf(v) - 1.f; }
__device__ __forceinline__ floatx4 mfma16(short8 a, short8 b, floatx4 c) {
  return __builtin_amdgcn_mfma_f32_16x16x32_bf16(a, b, c, 0, 0, 0);
}

// ws layout (bf16): [0,8192) embT[e][k] (k<40 Wv, else Wp) | [8192,24576) wT0[e][k] | [24576,40960) wT1[e][k]
// Total: 40960 shorts = exactly 81920 B. DO NOT EXCEED (ws_size appears to be 80 KiB).
__global__ void prep_weights(const float* __restrict__ Wv, const float* __restrict__ Wp,
                             const float* __restrict__ w0, const float* __restrict__ w1,
                             short* __restrict__ ws) {
  int idx = blockIdx.x * 256 + threadIdx.x;          // 160 blocks x 256 = 40960
  if (idx < 8192) {
    int e = idx >> 6, k = idx & 63;
    float v = (k < 40) ? Wv[(size_t)k * EMB + e] : Wp[(size_t)(k - 40) * EMB + e];
    ws[idx] = f2bf(v);
  } else if (idx < 24576) {
    int t = idx - 8192; int e = t >> 7, k = t & 127;
    ws[idx] = f2bf(w0[(size_t)k * EMB + e]);
  } else {
    int t = idx - 24576; int e = t >> 7, k = t & 127;
    ws[idx] = f2bf(w1[(size_t)k * EMB + e]);
  }
}

__global__ __launch_bounds__(256, 6) void gnn_fused(
    const float* __restrict__ obs,
    const float* __restrict__ bv, const float* __restrict__ bp,
    const float* __restrict__ as0, const float* __restrict__ ad0,
    const float* __restrict__ as1, const float* __restrict__ ad1,
    const short* __restrict__ wsb,
    float* __restrict__ out)
{
  __shared__ __align__(16) short s_x[32 * XSTR];       // 8704 B: x[token][e]
  __shared__ __align__(16) short s_h[4 * 32 * HSTR];   // 10240 B: 4 wave-private hT quarters

  const int tid  = threadIdx.x;
  const int lane = tid & 63;
  const int wv   = tid >> 6;      // 0..3 = head; e-rows [32wv,32wv+32); m-tiles {2wv,2wv+1}
  const int col  = lane & 15;
  const int quad = lane >> 4;
  const size_t b = blockIdx.x;

  const float* orow = obs + b * OBSL;
  short* hbase = &s_h[wv * 1280];               // own hT quarter: [32 e-loc][HSTR]
  const short8  z8 = {0,0,0,0,0,0,0,0};
  const floatx4 fz = {0.f,0.f,0.f,0.f};

  // ---------------- alive mask (wave-uniform), pad, scatter (proven pieces) ----------------
  unsigned m32; float invc;
  {
    float araw = (lane < NTOK) ? orow[1024 + lane] : 0.f;
    bool alv = (lane < NTOK) && (araw >= 0.5f);
    unsigned long long m = __ballot(alv);
    int cnt = __popcll(m);
    unsigned mm = (unsigned)m;
    if (cnt == 0) { mm = 0xFFFFFFFFu; cnt = NTOK; }
    m32 = mm; invc = 1.f / (float)cnt;
  }

  {                                             // complement pad: veh rows cols [40,64), ped rows cols [0,40)
    int idx = tid; int r = -1, k = 0;
    if (idx < 48)       { r = (idx * 171) >> 9;  k = 40 + (idx - r * 3) * 8; }       // /3 magic (idx<48)
    else if (idx < 128) { int t2 = idx - 48; int q5 = (t2 * 205) >> 10; r = 16 + q5; k = (t2 - q5 * 5) * 8; } // /5 magic (t2<80)
    if (r >= 0) *(short8*)&s_x[r * XSTR + k] = z8;
  }
  {                                             // scatter: 256 float4, 64 per wave; disjoint from pad
    int i4 = wv * 64 + lane;
    float4 v = *(const float4*)&orow[i4 * 4];
    int r, k;
    if (i4 < 160) { r = (i4 * 205) >> 11;  k = (i4 - r * 10) * 4; }              // /10 magic (i4<160)
    else { int t2 = i4 - 160; int q6 = (t2 * 171) >> 10; r = 16 + q6; k = 40 + (t2 - q6 * 6) * 4; } // /6 magic (t2<96)
    uint2v u; u.x = pk2(v.x, v.y); u.y = pk2(v.z, v.w);   // VMEM/VALU-fed: safe
    *(uint2v*)&s_x[r * XSTR + k] = u;
  }
  __syncthreads();                              // barS: pad+scatter -> Bxin reads

  // ---------------- P1: embed D[e][tok] (LDS-staged, proven path) ----------------
  {
    short8 Bxin[2][2];                          // full K=64 of x_in
    #pragma unroll
    for (int nt = 0; nt < 2; ++nt)
      #pragma unroll
      for (int kt = 0; kt < 2; ++kt)
        Bxin[nt][kt] = *(const short8*)&s_x[(nt * 16 + col) * XSTR + kt * 32 + quad * 8];
    __syncthreads();                            // barX: Bxin reads -> embed writes
    const short* embT = wsb;
    #pragma unroll
    for (int mi = 0; mi < 2; ++mi) {
      const int mtE = wv * 2 + mi;
      short8 A0 = *(const short8*)&embT[(mtE * 16 + col) * 64 + quad * 8];
      short8 A1 = *(const short8*)&embT[(mtE * 16 + col) * 64 + 32 + quad * 8];
      float4 bv4 = *(const float4*)&bv[mtE * 16 + quad * 4];
      float4 bp4 = *(const float4*)&bp[mtE * 16 + quad * 4];
      #pragma unroll
      for (int nt = 0; nt < 2; ++nt) {
        floatx4 acc = fz;
        acc = mfma16(A0, Bxin[nt][0], acc);
        acc = mfma16(A1, Bxin[nt][1], acc);
        float4 bb = nt ? bp4 : bv4;
        // pk2 inputs are VALU add results (acc+bias): safe
        uint2v u; u.x = pk2(acc[0] + bb.x, acc[1] + bb.y); u.y = pk2(acc[2] + bb.z, acc[3] + bb.w);
        *(uint2v*)&s_x[(nt * 16 + col) * XSTR + mtE * 16 + quad * 4] = u;
      }
    }
  }

  // ---------------- GAT layers ----------------
  for (int L = 0; L < 2; ++L) {
    const short* wT  = wsb + 8192 + L * 16384;
    const float* gas = L ? as1 : as0;
    const float* gad = L ? ad1 : ad0;

    __syncthreads();                            // barG: x writes (embed / L0 epilogue) -> GEMM reads

    // hT GEMM split by nt (register diet): acc[2] (8 AGPRs) live per pass; A re-read
    // per nt. Per-nt kt/mi order identical to v15 -> bit-identical results.
    // hT pack via f2bf (plain C): the v13/v16/v17/v18 red series was pk2 reading raw
    // MFMA accumulators (INLINEASM opaque to the hazard recognizer; proven by v19).
    float psrc[2], pdst[2];
    #pragma unroll
    for (int nt = 0; nt < 2; ++nt) {
      floatx4 acc[2];
      acc[0] = fz; acc[1] = fz;
      #pragma unroll
      for (int kt = 0; kt < 4; ++kt) {
        short8 Bn = *(const short8*)&s_x[(nt * 16 + col) * XSTR + kt * 32 + quad * 8];
        #pragma unroll
        for (int mi = 0; mi < 2; ++mi) {
          const int mt = wv * 2 + mi;
          short8 A = *(const short8*)&wT[(mt * 16 + col) * 128 + kt * 32 + quad * 8];
          acc[mi] = mfma16(A, Bn, acc[mi]);
        }
      }
      // alpha partials + hT writes for this nt (own head; wave-private quarter)
      float ps = 0.f, pd = 0.f;
      #pragma unroll
      for (int mi = 0; mi < 2; ++mi) {
        const int mt = wv * 2 + mi;
        float4 cs = *(const float4*)&gas[mt * 16 + quad * 4];
        float4 cd = *(const float4*)&gad[mt * 16 + quad * 4];
        floatx4 a = acc[mi];
        ps += a[0]*cs.x + a[1]*cs.y + a[2]*cs.z + a[3]*cs.w;
        pd += a[0]*cd.x + a[1]*cd.y + a[2]*cd.z + a[3]*cd.w;
        const int rowloc = mi * 16 + quad * 4;  // e-local row within quarter
        unsigned short* hrow = (unsigned short*)&hbase[rowloc * HSTR + nt * 16 + col];
        hrow[0]        = (unsigned short)f2bf(a[0]);
        hrow[HSTR]     = (unsigned short)f2bf(a[1]);
        hrow[2 * HSTR] = (unsigned short)f2bf(a[2]);
        hrow[3 * HSTR] = (unsigned short)f2bf(a[3]);
      }
      psrc[nt] = ps; pdst[nt] = pd;
    }

    // full per-token alpha in every lane (token = nt*16 + col), exp2 domain
    #pragma unroll
    for (int nt = 0; nt < 2; ++nt) {
      float vs = psrc[nt]; vs += __shfl_xor(vs, 16); vs += __shfl_xor(vs, 32);
      psrc[nt] = vs * 1.44269504088896340736f;
      float vd = pdst[nt]; vd += __shfl_xor(vd, 16); vd += __shfl_xor(vd, 32);
      pdst[nt] = vd * 1.44269504088896340736f;
    }

    // softmax (own head), PV B-frag layout: lane owns (i = ii*16+col, key = quad*8+jj)
    short8 pf[2];
    {
      float vsel = (quad >> 1) ? pdst[1] : pdst[0];
      float ad8[8];
      #pragma unroll
      for (int jj = 0; jj < 8; ++jj) {
        float v = __shfl(vsel, ((quad >> 1) << 5) + ((quad & 1) << 3) + jj);
        bool alive = (m32 >> (quad * 8 + jj)) & 1u;        // SGPR mask test
        ad8[jj] = alive ? v : -1e30f;                      // dead keys -> exp2 -> 0
      }
      #pragma unroll
      for (int ii = 0; ii < 2; ++ii) {
        float ai = psrc[ii];
        float ev[8]; float sum = 0.f;
        #pragma unroll
        for (int jj = 0; jj < 8; ++jj) {
          float e = ai + ad8[jj];
          e = fmaxf(e, 0.2f * e);                          // leaky-relu (commutes with log2e scale)
          float p = exp2_hw(e);
          ev[jj] = p; sum += p;
        }
        sum += __shfl_xor(sum, 16);
        sum += __shfl_xor(sum, 32);
        float inv = rcp_hw(sum);
        union { unsigned u4[4]; short8 s; } pu;
        #pragma unroll
        for (int p2 = 0; p2 < 4; ++p2) pu.u4[p2] = pk2(ev[2*p2] * inv, ev[2*p2+1] * inv); // VALU-fed: safe
        pf[ii] = pu.s;
      }
    }

    // PV A-frags from own quarter (same-wave), proven position: BEFORE barE
    short8 Ah[2];
    #pragma unroll
    for (int mt2 = 0; mt2 < 2; ++mt2)
      Ah[mt2] = *(const short8*)&hbase[(mt2 * 16 + col) * HSTR + quad * 8];
    if (L == 0) __syncthreads();                // barE: ALL waves' GEMM x-reads done -> x_next writes

    #pragma unroll
    for (int mt2 = 0; mt2 < 2; ++mt2) {
      floatx4 po[2];
      #pragma unroll
      for (int nt = 0; nt < 2; ++nt) {
        po[nt] = mfma16(Ah[mt2], pf[nt], fz);
      }
      const int ecol = wv * 32 + mt2 * 16 + quad * 4;  // global e
      if (L == 0) {
        #pragma unroll
        for (int nt = 0; nt < 2; ++nt) {
          // pk2 inputs are elu1() VALU results: safe
          uint2v u;
          u.x = pk2(elu1(po[nt][0]), elu1(po[nt][1]));
          u.y = pk2(elu1(po[nt][2]), elu1(po[nt][3]));
          *(uint2v*)&s_x[(nt * 16 + col) * XSTR + ecol] = u;
        }
      } else {
        float aI0 = ((m32 >> col) & 1u) ? 1.f : 0.f;         // alive of token col
        float aI1 = ((m32 >> (16 + col)) & 1u) ? 1.f : 0.f;  // alive of token 16+col
        #pragma unroll
        for (int r = 0; r < 4; ++r) {
          float s = elu1(po[0][r]) * aI0 + elu1(po[1][r]) * aI1;
          s += __shfl_xor(s, 1); s += __shfl_xor(s, 2);
          s += __shfl_xor(s, 4); s += __shfl_xor(s, 8);
          if (col == 0) out[b * EMB + ecol + r] = s * invc;  // direct store (proven path)
        }
      }
    }
  }
}

extern "C" void kernel_launch(void* const* d_in, const int* in_sizes, int n_in,
                              void* d_out, int out_size, void* d_ws, size_t ws_size,
                              hipStream_t stream) {
  const float* obs = (const float*)d_in[0];
  const float* Wv  = (const float*)d_in[1];
  const float* bv  = (const float*)d_in[2];
  const float* Wp  = (const float*)d_in[3];
  const float* bp  = (const float*)d_in[4];
  const float* w0  = (const float*)d_in[5];
  const float* as0 = (const float*)d_in[6];
  const float* ad0 = (const float*)d_in[7];
  const float* w1  = (const float*)d_in[8];
  const float* as1 = (const float*)d_in[9];
  const float* ad1 = (const float*)d_in[10];
  float* out = (float*)d_out;
  short* wsb = (short*)d_ws;                      // uses exactly 80 KiB

  int Bn = in_sizes[0] / OBSL;                    // 4096
  prep_weights<<<160, 256, 0, stream>>>(Wv, Wp, w0, w1, wsb);
  gnn_fused<<<Bn, 256, 0, stream>>>(obs, bv, bp, as0, ad0, as1, ad1, wsb, out);
}